// Round 1
// baseline (20.841 us; speedup 1.0000x reference)
//
#include <hip/hip_runtime.h>
#include <hip/hip_bf16.h>

#define D 64
#define BU 1024
#define BI 4096
#define L 50

typedef __attribute__((ext_vector_type(4))) float f32x4;
typedef __attribute__((ext_vector_type(8))) short bf16x8;

__device__ __forceinline__ ushort f2bf(float x) {
    union { float f; unsigned u; } v; v.f = x;
    unsigned r = v.u + 0x7fff + ((v.u >> 16) & 1);  // round-to-nearest-even
    return (ushort)(r >> 16);
}

// One wave per user (thread = latent dim). eff[u][d] = uw[uid][d] + sum_l v*We[idx][d]
__global__ __launch_bounds__(256) void k_eff(
    const int* __restrict__ user_ids, const int* __restrict__ fb_idx,
    const float* __restrict__ fb_val, const float* __restrict__ uw,
    const float* __restrict__ ub, const float* __restrict__ We,
    ushort* __restrict__ eff, float* __restrict__ ubg) {
    const int u = blockIdx.x * 4 + (threadIdx.x >> 6);
    const int d = threadIdx.x & 63;
    const int uid = user_ids[u];
    float acc = uw[uid * D + d];
    const int*   __restrict__ ip = fb_idx + u * L;
    const float* __restrict__ vp = fb_val + u * L;
    #pragma unroll 10
    for (int l = 0; l < L; ++l)
        acc = fmaf(vp[l], We[ip[l] * D + d], acc);
    eff[u * D + d] = f2bf(acc);
    if (d == 0) ubg[u] = ub[uid];
}

// Gather + bf16-convert item rows; gather item bias.
__global__ __launch_bounds__(256) void k_items(
    const int* __restrict__ item_ids, const float* __restrict__ iw,
    const float* __restrict__ ib, ushort* __restrict__ iwg,
    float* __restrict__ ibg) {
    const int n = blockIdx.x * 4 + (threadIdx.x >> 6);
    const int d = threadIdx.x & 63;
    const int iid = item_ids[n];
    iwg[n * D + d] = f2bf(iw[iid * D + d]);
    if (d == 0) ibg[n] = ib[iid];
}

// Per-wave 16(M)x64(N) tile via 8x mfma_f32_16x16x32_bf16, K=64. No LDS:
// both eff [M][K] and iwg [N][K] are K-contiguous -> each lane loads 16B frags.
__global__ __launch_bounds__(256) void k_gemm(
    const ushort* __restrict__ eff, const ushort* __restrict__ iwg,
    const float* __restrict__ ubg, const float* __restrict__ ibg,
    const float* __restrict__ bias, float* __restrict__ out) {
    const int lane = threadIdx.x & 63;
    const int wave = threadIdx.x >> 6;
    const int m0 = blockIdx.y * 16;
    const int n0 = blockIdx.x * 256 + wave * 64;
    const int lr = lane & 15;   // A row / B col / C col (within 16)
    const int g  = lane >> 4;   // k-group (8 elems each)

    const bf16x8 a0 = *(const bf16x8*)(eff + (m0 + lr) * D + g * 8);
    const bf16x8 a1 = *(const bf16x8*)(eff + (m0 + lr) * D + 32 + g * 8);

    f32x4 acc[4];
    #pragma unroll
    for (int c = 0; c < 4; ++c) {
        acc[c] = (f32x4){0.f, 0.f, 0.f, 0.f};
        const int col = n0 + c * 16 + lr;
        const bf16x8 b0 = *(const bf16x8*)(iwg + col * D + g * 8);
        const bf16x8 b1 = *(const bf16x8*)(iwg + col * D + 32 + g * 8);
        acc[c] = __builtin_amdgcn_mfma_f32_16x16x32_bf16(a0, b0, acc[c], 0, 0, 0);
        acc[c] = __builtin_amdgcn_mfma_f32_16x16x32_bf16(a1, b1, acc[c], 0, 0, 0);
    }

    const float bb = bias[0];
    float ubr[4];
    #pragma unroll
    for (int r = 0; r < 4; ++r) ubr[r] = ubg[m0 + g * 4 + r];

    #pragma unroll
    for (int c = 0; c < 4; ++c) {
        const int col = n0 + c * 16 + lr;
        const float ibc = ibg[col] + bb;
        #pragma unroll
        for (int r = 0; r < 4; ++r)
            out[(size_t)(m0 + g * 4 + r) * BI + col] = acc[c][r] + ubr[r] + ibc;
    }
}

extern "C" void kernel_launch(void* const* d_in, const int* in_sizes, int n_in,
                              void* d_out, int out_size, void* d_ws, size_t ws_size,
                              hipStream_t stream) {
    const int*   user_ids = (const int*)  d_in[0];
    const int*   item_ids = (const int*)  d_in[1];
    const int*   fb_idx   = (const int*)  d_in[2];
    const float* fb_val   = (const float*)d_in[3];
    const float* uw       = (const float*)d_in[4];
    const float* ub       = (const float*)d_in[5];
    const float* iw       = (const float*)d_in[6];
    const float* ib       = (const float*)d_in[7];
    const float* bias     = (const float*)d_in[8];
    const float* We       = (const float*)d_in[9];

    char* ws = (char*)d_ws;
    ushort* eff = (ushort*)(ws);                         // 1024*64*2   = 131072 B
    ushort* iwg = (ushort*)(ws + 131072);                // 4096*64*2   = 524288 B
    float*  ubg = (float*)(ws + 131072 + 524288);        // 1024*4      = 4096 B
    float*  ibg = (float*)(ws + 131072 + 524288 + 4096); // 4096*4      = 16384 B

    float* out = (float*)d_out;

    k_eff<<<BU / 4, 256, 0, stream>>>(user_ids, fb_idx, fb_val, uw, ub, We, eff, ubg);
    k_items<<<BI / 4, 256, 0, stream>>>(item_ids, iw, ib, iwg, ibg);
    k_gemm<<<dim3(BI / 256, BU / 16), 256, 0, stream>>>(eff, iwg, ubg, ibg, bias, out);
}